// Round 8
// baseline (177.572 us; speedup 1.0000x reference)
//
#include <hip/hip_runtime.h>

#define BB 8
#define NN 1024
#define DIN 64
#define DOUT 64
#define EMB 16
#define DPC 16

typedef __attribute__((ext_vector_type(8))) short bf16x8;
typedef __attribute__((ext_vector_type(4))) float f32x4;

__device__ inline unsigned short f2bf(float f) {
    unsigned u = __float_as_uint(f);
    u += 0x7fffu + ((u >> 16) & 1u);      // RNE (finite only)
    return (unsigned short)(u >> 16);
}

// =======================================================================
// K1: blocks [0,512): z — Z, Sub (coalesced), xzT.
//     blocks [512,768): wgen — W2 bf16.
//     blocks [768,1792): sim — 1 row each.
// =======================================================================
__global__ __launch_bounds__(256) void k_front(const float* __restrict__ E,
                                               const float* __restrict__ pa,
                                               const float* __restrict__ x,
                                               const float* __restrict__ wp,
                                               unsigned short* __restrict__ sim_bf,
                                               unsigned short* __restrict__ Sub,
                                               unsigned short* __restrict__ xzT,
                                               unsigned short* __restrict__ W2) {
    __shared__ __align__(16) char smem[34816];
    const int bid = blockIdx.x, tid = threadIdx.x;
    const int lane = tid & 63, wave = tid >> 6;

    if (bid < 512) {
        // ---------------- z: 16 c-rows per block ----------------
        const int b = bid >> 6, c0 = (bid & 63) * 16;
        float* pa_l  = (float*)smem;                 // 32 KB (reused as xl)
        float* zpart = (float*)(smem + 32768);       // 256 f
        float* invZ  = (float*)(smem + 33792);       // 16 f

        const int cs = tid >> 4, jq = tid & 15;      // row, j-phase
        float myc[DPC];
        #pragma unroll
        for (int p4 = 0; p4 < 4; ++p4) {
            float4 t = *(const float4*)&pa[((size_t)b*NN + c0 + cs)*DPC + p4*4];
            myc[p4*4+0] = t.x; myc[p4*4+1] = t.y; myc[p4*4+2] = t.z; myc[p4*4+3] = t.w;
        }

        float part = 0.0f;
        for (int h = 0; h < 2; ++h) {
            __syncthreads();
            for (int i = tid; i < 2048; i += 256)
                ((float4*)pa_l)[i] = ((const float4*)(pa + ((size_t)b*NN + h*512)*DPC))[i];
            __syncthreads();
            unsigned short* subrow = Sub + ((size_t)b*NN + c0 + cs)*NN + h*512;
            for (int j8 = 0; j8 < 8; ++j8) {
                float e[4];
                #pragma unroll
                for (int t = 0; t < 4; ++t) {
                    int jj = j8*64 + jq*4 + t;
                    float s = 0.0f;
                    #pragma unroll
                    for (int p4 = 0; p4 < 4; ++p4) {
                        float4 qv = *(const float4*)&pa_l[jj*DPC + p4*4];
                        s += fabsf(myc[p4*4+0]-qv.x) + fabsf(myc[p4*4+1]-qv.y)
                           + fabsf(myc[p4*4+2]-qv.z) + fabsf(myc[p4*4+3]-qv.w);
                    }
                    e[t] = __expf(-s);
                }
                part += e[0] + e[1] + e[2] + e[3];
                // 16 adjacent lanes (jq=0..15) cover 64 consecutive j -> 128 B contiguous
                *(ushort4*)&subrow[j8*64 + jq*4] =
                    make_ushort4(f2bf(e[0]), f2bf(e[1]), f2bf(e[2]), f2bf(e[3]));
            }
        }
        zpart[cs*16 + jq] = part;
        __syncthreads();
        float* xl = pa_l;                            // xl[16][65]
        #pragma unroll
        for (int i = 0; i < 4; ++i) {
            int l = i*256 + tid, d = l & 63, c = l >> 6;
            xl[c*65 + d] = x[((size_t)b*NN + c0 + c)*DIN + d];
        }
        if (tid < 16) {
            float z = 0.f;
            #pragma unroll
            for (int q2 = 0; q2 < 16; ++q2) z += zpart[tid*16 + q2];
            invZ[tid] = 1.0f / z;
        }
        __syncthreads();
        #pragma unroll
        for (int i = 0; i < 4; ++i) {
            int l = i*256 + tid, c = l & 15, d = l >> 4;
            xzT[((size_t)b*DIN + d)*NN + c0 + c] = f2bf(xl[c*65 + d] * invZ[c]);
        }
    } else if (bid < 768) {
        // ---------------- wgen: 32 n-rows x 1024 kio per block ----------------
        const int idx = bid - 512;
        const int kio0 = (idx & 7) * 1024 + tid * 4;
        const int n0 = (idx >> 3) * 32;
        float* El = (float*)smem;                    // 32*16 f
        if (tid < 128) *(float4*)&El[tid*4] = *(const float4*)&E[n0*EMB + tid*4];

        float4 wq[EMB];
        #pragma unroll
        for (int d = 0; d < EMB; ++d)
            wq[d] = *(const float4*)&wp[d*8192 + kio0];
        __syncthreads();

        for (int n = 0; n < 32; ++n) {
            float4 a = make_float4(0.f, 0.f, 0.f, 0.f);
            #pragma unroll
            for (int d = 0; d < EMB; ++d) {
                float e = El[n*EMB + d];
                a.x += e*wq[d].x; a.y += e*wq[d].y; a.z += e*wq[d].z; a.w += e*wq[d].w;
            }
            *(ushort4*)&W2[(size_t)(n0 + n)*8192 + kio0] =
                make_ushort4(f2bf(a.x), f2bf(a.y), f2bf(a.z), f2bf(a.w));
        }
    } else {
        // ---------------- sim: 1 row per block ----------------
        const int row = bid - 768;
        float* redw = (float*)smem;
        float4 ei0 = *(const float4*)&E[row*EMB + 0];
        float4 ei1 = *(const float4*)&E[row*EMB + 4];
        float4 ei2 = *(const float4*)&E[row*EMB + 8];
        float4 ei3 = *(const float4*)&E[row*EMB + 12];

        float rv[4], tmax = -1e30f;
        #pragma unroll
        for (int k = 0; k < 4; ++k) {
            int j = tid + k*256;
            float4 a0 = *(const float4*)&E[j*EMB + 0];
            float4 a1 = *(const float4*)&E[j*EMB + 4];
            float4 a2 = *(const float4*)&E[j*EMB + 8];
            float4 a3 = *(const float4*)&E[j*EMB + 12];
            float s = ei0.x*a0.x + ei0.y*a0.y + ei0.z*a0.z + ei0.w*a0.w
                    + ei1.x*a1.x + ei1.y*a1.y + ei1.z*a1.z + ei1.w*a1.w
                    + ei2.x*a2.x + ei2.y*a2.y + ei2.z*a2.z + ei2.w*a2.w
                    + ei3.x*a3.x + ei3.y*a3.y + ei3.z*a3.z + ei3.w*a3.w;
            s = fmaxf(s, 0.0f);
            rv[k] = s; tmax = fmaxf(tmax, s);
        }
        #pragma unroll
        for (int off = 32; off > 0; off >>= 1) tmax = fmaxf(tmax, __shfl_xor(tmax, off));
        if (lane == 0) redw[wave] = tmax;
        __syncthreads();
        float rmax = fmaxf(fmaxf(redw[0], redw[1]), fmaxf(redw[2], redw[3]));
        __syncthreads();

        float ev[4], tsum = 0.f;
        #pragma unroll
        for (int k = 0; k < 4; ++k) { ev[k] = __expf(rv[k] - rmax); tsum += ev[k]; }
        #pragma unroll
        for (int off = 32; off > 0; off >>= 1) tsum += __shfl_xor(tsum, off);
        if (lane == 0) redw[wave] = tsum;
        __syncthreads();
        float inv = 1.0f / (redw[0] + redw[1] + redw[2] + redw[3]);
        #pragma unroll
        for (int k = 0; k < 4; ++k)
            sim_bf[(size_t)row*NN + tid + k*256] = f2bf(ev[k] * inv);
    }
}

// =======================================================================
// Barrier-free, LDS-free MFMA GEMM: each wave owns a 16m x 16d tile and
// loads A/B fragments straight from global (frag = contiguous 16 B/lane).
// A[r][k], B[d][k] both row-major over k (K = 1024).
// =======================================================================
__device__ inline f32x4 wave_gemm(const unsigned short* __restrict__ Arow,
                                  const unsigned short* __restrict__ Brow,
                                  int lane) {
    const int q = lane >> 4, r = lane & 15;
    const unsigned short* ap = Arow + (size_t)r*NN + q*8;
    const unsigned short* bp = Brow + (size_t)r*NN + q*8;
    f32x4 acc = {0.f, 0.f, 0.f, 0.f};
    #pragma unroll 8
    for (int kk = 0; kk < 32; ++kk) {
        bf16x8 af = *(const bf16x8*)(ap + kk*32);
        bf16x8 bf = *(const bf16x8*)(bp + kk*32);
        acc = __builtin_amdgcn_mfma_f32_16x16x32_bf16(af, bf, acc, 0, 0, 0);
    }
    return acc;
}

// K2: sx = Sub @ xz. 512 blocks x 4 waves = 2048 wave-tiles (b, m-tile, d-tile).
__global__ __launch_bounds__(256) void k_sx5(const unsigned short* __restrict__ Sub,
                                             const unsigned short* __restrict__ xzT,
                                             float* __restrict__ sx,
                                             unsigned short* __restrict__ sxT) {
    const int tid = threadIdx.x, lane = tid & 63;
    const int wid = blockIdx.x * 4 + (tid >> 6);
    const int b = wid >> 8, rem = wid & 255;
    const int m0 = (rem >> 2) * 16, d0 = (rem & 3) * 16;

    f32x4 acc = wave_gemm(Sub + ((size_t)b*NN + m0)*NN,
                          xzT + ((size_t)b*DIN + d0)*NN, lane);

    const int q = lane >> 4, r = lane & 15;
    const int d = d0 + r, mrow = m0 + q*4;
    #pragma unroll
    for (int reg = 0; reg < 4; ++reg)
        sx[((size_t)b*NN + mrow + reg)*DIN + d] = acc[reg];
    *(ushort4*)&sxT[((size_t)b*DIN + d)*NN + mrow] =
        make_ushort4(f2bf(acc[0]), f2bf(acc[1]), f2bf(acc[2]), f2bf(acc[3]));
}

// K3: y = sim @ sx (B from sxT). Same tiling.
__global__ __launch_bounds__(256) void k_y5(const unsigned short* __restrict__ sim_bf,
                                            const unsigned short* __restrict__ sxT,
                                            float* __restrict__ y) {
    const int tid = threadIdx.x, lane = tid & 63;
    const int wid = blockIdx.x * 4 + (tid >> 6);
    const int b = wid >> 8, rem = wid & 255;
    const int m0 = (rem >> 2) * 16, d0 = (rem & 3) * 16;

    f32x4 acc = wave_gemm(sim_bf + (size_t)m0*NN,
                          sxT + ((size_t)b*DIN + d0)*NN, lane);

    const int q = lane >> 4, r = lane & 15;
    const int d = d0 + r, mrow = m0 + q*4;
    #pragma unroll
    for (int reg = 0; reg < 4; ++reg)
        y[((size_t)b*NN + mrow + reg)*DIN + d] = acc[reg];
}

// =======================================================================
// K4: out[b,n,o] = sum_ki [sx;y][b,n,ki] * W2[n,ki,o] + E[n]@bp. 1024 blocks.
// =======================================================================
__global__ __launch_bounds__(256) void k_out2(const float* __restrict__ E,
                                              const float* __restrict__ bp,
                                              const unsigned short* __restrict__ W2,
                                              const float* __restrict__ sxin,
                                              const float* __restrict__ yin,
                                              float* __restrict__ out) {
    const int n = blockIdx.x;
    const int tid = threadIdx.x;
    __shared__ __align__(16) uint4 W2l4[1024];
    __shared__ float vl[BB * 128];
    __shared__ float El2[EMB];

    if (tid < EMB) El2[tid] = E[n*EMB + tid];
    {
        const uint4* src = (const uint4*)(W2 + (size_t)n * 8192);
        #pragma unroll
        for (int r = 0; r < 4; ++r) W2l4[tid + r*256] = src[tid + r*256];
    }
    for (int idx = tid; idx < BB*128; idx += 256) {
        int b_ = idx >> 7, ki = idx & 127;
        vl[idx] = (ki < 64) ? sxin[((size_t)b_*NN + n)*DIN + ki]
                            : yin[((size_t)b_*NN + n)*DIN + (ki - 64)];
    }
    __syncthreads();

    const int b_ = tid >> 5, op = (tid & 31) * 2;
    const unsigned* W2u = (const unsigned*)W2l4;
    float a0 = 0.f, a1 = 0.f;
    #pragma unroll 4
    for (int ki = 0; ki < 128; ++ki) {
        float vv = vl[b_*128 + ki];
        unsigned w2 = W2u[ki*32 + (op >> 1)];
        a0 += vv * __uint_as_float(w2 << 16);
        a1 += vv * __uint_as_float(w2 & 0xffff0000u);
    }
    float b0 = 0.f, b1 = 0.f;
    #pragma unroll
    for (int d = 0; d < EMB; ++d) {
        float e = El2[d];
        b0 += e * bp[d*DOUT + op];
        b1 += e * bp[d*DOUT + op + 1];
    }
    *(float2*)&out[((size_t)b_*NN + n)*DOUT + op] = make_float2(a0 + b0, a1 + b1);
}

extern "C" void kernel_launch(void* const* d_in, const int* in_sizes, int n_in,
                              void* d_out, int out_size, void* d_ws, size_t ws_size,
                              hipStream_t stream) {
    (void)in_sizes; (void)n_in; (void)out_size; (void)ws_size;
    const float* x  = (const float*)d_in[0];
    const float* E  = (const float*)d_in[1];
    const float* pa = (const float*)d_in[2];
    const float* wp = (const float*)d_in[3];
    const float* bp = (const float*)d_in[4];
    float* out = (float*)d_out;

    unsigned short* ws16   = (unsigned short*)d_ws;
    unsigned short* sim_bf = ws16;                       // 1,048,576 us
    unsigned short* xzT    = sim_bf + (size_t)NN*NN;     //   524,288 us
    unsigned short* sxT    = xzT + (size_t)BB*DIN*NN;    //   524,288 us
    unsigned short* Sub    = sxT + (size_t)BB*DIN*NN;    // 8,388,608 us
    unsigned short* W2     = Sub + (size_t)BB*NN*NN;     // 8,388,608 us
    float* sx = (float*)(W2 + (size_t)NN*2*DIN*DOUT);    //   524,288 f
    float* y  = sx + (size_t)BB*NN*DIN;                  //   524,288 f

    k_front<<<1792, 256, 0, stream>>>(E, pa, x, wp, sim_bf, Sub, xzT, W2);
    k_sx5<<<512, 256, 0, stream>>>(Sub, xzT, sx, sxT);
    k_y5<<<512, 256, 0, stream>>>(sim_bf, sxT, y);
    k_out2<<<NN, 256, 0, stream>>>(E, bp, W2, sx, y, out);
}

// Round 9
// 133.132 us; speedup vs baseline: 1.3338x; 1.3338x over previous
//
#include <hip/hip_runtime.h>

#define BB 8
#define NN 1024
#define DIN 64
#define DOUT 64
#define EMB 16
#define DPC 16

typedef __attribute__((ext_vector_type(8))) short bf16x8;
typedef __attribute__((ext_vector_type(4))) float f32x4;

__device__ inline unsigned short f2bf(float f) {
    unsigned u = __float_as_uint(f);
    u += 0x7fffu + ((u >> 16) & 1u);      // RNE (finite only)
    return (unsigned short)(u >> 16);
}

// =======================================================================
// K1: blocks [0,512): z — Z, Sub, xzT (round-7 broadcast-read mapping).
//     blocks [512,768): wgen — W2 bf16.
//     blocks [768,1792): sim — 1 row each.
// =======================================================================
__global__ __launch_bounds__(256) void k_front(const float* __restrict__ E,
                                               const float* __restrict__ pa,
                                               const float* __restrict__ x,
                                               const float* __restrict__ wp,
                                               unsigned short* __restrict__ sim_bf,
                                               unsigned short* __restrict__ Sub,
                                               unsigned short* __restrict__ xzT,
                                               unsigned short* __restrict__ W2) {
    __shared__ __align__(16) char smem[34816];
    const int bid = blockIdx.x, tid = threadIdx.x;
    const int lane = tid & 63, wave = tid >> 6;

    if (bid < 512) {
        // ---------------- z: 16 c-rows per block, broadcast pa_l reads ----------------
        const int b = bid >> 6, c0 = (bid & 63) * 16;
        float* pa_l  = (float*)smem;                 // 32 KB (reused as xl)
        float* zpart = (float*)(smem + 32768);       // 256 f
        float* invZ  = (float*)(smem + 33792);       // 16 f

        const int cs = tid & 15, jq = tid >> 4;      // row, j-group (32 j each)
        float myc[DPC];
        #pragma unroll
        for (int p4 = 0; p4 < 4; ++p4) {
            float4 t = *(const float4*)&pa[((size_t)b*NN + c0 + cs)*DPC + p4*4];
            myc[p4*4+0] = t.x; myc[p4*4+1] = t.y; myc[p4*4+2] = t.z; myc[p4*4+3] = t.w;
        }

        float part = 0.0f;
        for (int h = 0; h < 2; ++h) {
            __syncthreads();
            for (int i = tid; i < 2048; i += 256)
                ((float4*)pa_l)[i] = ((const float4*)(pa + ((size_t)b*NN + h*512)*DPC))[i];
            __syncthreads();
            unsigned short* subrow = Sub + ((size_t)b*NN + c0 + cs)*NN + h*512 + jq*32;
            for (int j8 = 0; j8 < 8; ++j8) {
                float e[4];
                #pragma unroll
                for (int t = 0; t < 4; ++t) {
                    int jj = jq*32 + j8*4 + t;
                    float s = 0.0f;
                    #pragma unroll
                    for (int p4 = 0; p4 < 4; ++p4) {
                        float4 qv = *(const float4*)&pa_l[jj*DPC + p4*4];
                        s += fabsf(myc[p4*4+0]-qv.x) + fabsf(myc[p4*4+1]-qv.y)
                           + fabsf(myc[p4*4+2]-qv.z) + fabsf(myc[p4*4+3]-qv.w);
                    }
                    e[t] = __expf(-s);
                }
                part += e[0] + e[1] + e[2] + e[3];
                *(ushort4*)&subrow[j8*4] =
                    make_ushort4(f2bf(e[0]), f2bf(e[1]), f2bf(e[2]), f2bf(e[3]));
            }
        }
        zpart[jq*16 + cs] = part;
        __syncthreads();
        float* xl = pa_l;                            // xl[16][65]
        #pragma unroll
        for (int i = 0; i < 4; ++i) {
            int l = i*256 + tid, d = l & 63, c = l >> 6;
            xl[c*65 + d] = x[((size_t)b*NN + c0 + c)*DIN + d];
        }
        if (tid < 16) {
            float z = 0.f;
            #pragma unroll
            for (int q2 = 0; q2 < 16; ++q2) z += zpart[q2*16 + tid];
            invZ[tid] = 1.0f / z;
        }
        __syncthreads();
        #pragma unroll
        for (int i = 0; i < 4; ++i) {
            int l = i*256 + tid, c = l & 15, d = l >> 4;
            xzT[((size_t)b*DIN + d)*NN + c0 + c] = f2bf(xl[c*65 + d] * invZ[c]);
        }
    } else if (bid < 768) {
        // ---------------- wgen: 32 n-rows x 1024 kio per block ----------------
        const int idx = bid - 512;
        const int kio0 = (idx & 7) * 1024 + tid * 4;
        const int n0 = (idx >> 3) * 32;
        float* El = (float*)smem;                    // 32*16 f
        if (tid < 128) *(float4*)&El[tid*4] = *(const float4*)&E[n0*EMB + tid*4];

        float4 wq[EMB];
        #pragma unroll
        for (int d = 0; d < EMB; ++d)
            wq[d] = *(const float4*)&wp[d*8192 + kio0];
        __syncthreads();

        for (int n = 0; n < 32; ++n) {
            float4 a = make_float4(0.f, 0.f, 0.f, 0.f);
            #pragma unroll
            for (int d = 0; d < EMB; ++d) {
                float e = El[n*EMB + d];
                a.x += e*wq[d].x; a.y += e*wq[d].y; a.z += e*wq[d].z; a.w += e*wq[d].w;
            }
            *(ushort4*)&W2[(size_t)(n0 + n)*8192 + kio0] =
                make_ushort4(f2bf(a.x), f2bf(a.y), f2bf(a.z), f2bf(a.w));
        }
    } else {
        // ---------------- sim: 1 row per block ----------------
        const int row = bid - 768;
        float* redw = (float*)smem;
        float4 ei0 = *(const float4*)&E[row*EMB + 0];
        float4 ei1 = *(const float4*)&E[row*EMB + 4];
        float4 ei2 = *(const float4*)&E[row*EMB + 8];
        float4 ei3 = *(const float4*)&E[row*EMB + 12];

        float rv[4], tmax = -1e30f;
        #pragma unroll
        for (int k = 0; k < 4; ++k) {
            int j = tid + k*256;
            float4 a0 = *(const float4*)&E[j*EMB + 0];
            float4 a1 = *(const float4*)&E[j*EMB + 4];
            float4 a2 = *(const float4*)&E[j*EMB + 8];
            float4 a3 = *(const float4*)&E[j*EMB + 12];
            float s = ei0.x*a0.x + ei0.y*a0.y + ei0.z*a0.z + ei0.w*a0.w
                    + ei1.x*a1.x + ei1.y*a1.y + ei1.z*a1.z + ei1.w*a1.w
                    + ei2.x*a2.x + ei2.y*a2.y + ei2.z*a2.z + ei2.w*a2.w
                    + ei3.x*a3.x + ei3.y*a3.y + ei3.z*a3.z + ei3.w*a3.w;
            s = fmaxf(s, 0.0f);
            rv[k] = s; tmax = fmaxf(tmax, s);
        }
        #pragma unroll
        for (int off = 32; off > 0; off >>= 1) tmax = fmaxf(tmax, __shfl_xor(tmax, off));
        if (lane == 0) redw[wave] = tmax;
        __syncthreads();
        float rmax = fmaxf(fmaxf(redw[0], redw[1]), fmaxf(redw[2], redw[3]));
        __syncthreads();

        float ev[4], tsum = 0.f;
        #pragma unroll
        for (int k = 0; k < 4; ++k) { ev[k] = __expf(rv[k] - rmax); tsum += ev[k]; }
        #pragma unroll
        for (int off = 32; off > 0; off >>= 1) tsum += __shfl_xor(tsum, off);
        if (lane == 0) redw[wave] = tsum;
        __syncthreads();
        float inv = 1.0f / (redw[0] + redw[1] + redw[2] + redw[3]);
        #pragma unroll
        for (int k = 0; k < 4; ++k)
            sim_bf[(size_t)row*NN + tid + k*256] = f2bf(ev[k] * inv);
    }
}

// =======================================================================
// Barrier-free, LDS-free MFMA GEMM: each wave owns a 16m x 16d tile and
// loads A/B fragments straight from global (frag = contiguous 16 B/lane).
// =======================================================================
__device__ inline f32x4 wave_gemm(const unsigned short* __restrict__ Arow,
                                  const unsigned short* __restrict__ Brow,
                                  int lane) {
    const int q = lane >> 4, r = lane & 15;
    const unsigned short* ap = Arow + (size_t)r*NN + q*8;
    const unsigned short* bp = Brow + (size_t)r*NN + q*8;
    f32x4 acc = {0.f, 0.f, 0.f, 0.f};
    #pragma unroll 8
    for (int kk = 0; kk < 32; ++kk) {
        bf16x8 af = *(const bf16x8*)(ap + kk*32);
        bf16x8 bf = *(const bf16x8*)(bp + kk*32);
        acc = __builtin_amdgcn_mfma_f32_16x16x32_bf16(af, bf, acc, 0, 0, 0);
    }
    return acc;
}

// K2: sx = Sub @ xz. 512 blocks x 4 waves = 2048 wave-tiles (b, m-tile, d-tile).
__global__ __launch_bounds__(256) void k_sx5(const unsigned short* __restrict__ Sub,
                                             const unsigned short* __restrict__ xzT,
                                             float* __restrict__ sx,
                                             unsigned short* __restrict__ sxT) {
    const int tid = threadIdx.x, lane = tid & 63;
    const int wid = blockIdx.x * 4 + (tid >> 6);
    const int b = wid >> 8, rem = wid & 255;
    const int m0 = (rem >> 2) * 16, d0 = (rem & 3) * 16;

    f32x4 acc = wave_gemm(Sub + ((size_t)b*NN + m0)*NN,
                          xzT + ((size_t)b*DIN + d0)*NN, lane);

    const int q = lane >> 4, r = lane & 15;
    const int d = d0 + r, mrow = m0 + q*4;
    #pragma unroll
    for (int reg = 0; reg < 4; ++reg)
        sx[((size_t)b*NN + mrow + reg)*DIN + d] = acc[reg];
    *(ushort4*)&sxT[((size_t)b*DIN + d)*NN + mrow] =
        make_ushort4(f2bf(acc[0]), f2bf(acc[1]), f2bf(acc[2]), f2bf(acc[3]));
}

// K3: y = sim @ sx (B from sxT). Same tiling.
__global__ __launch_bounds__(256) void k_y5(const unsigned short* __restrict__ sim_bf,
                                            const unsigned short* __restrict__ sxT,
                                            float* __restrict__ y) {
    const int tid = threadIdx.x, lane = tid & 63;
    const int wid = blockIdx.x * 4 + (tid >> 6);
    const int b = wid >> 8, rem = wid & 255;
    const int m0 = (rem >> 2) * 16, d0 = (rem & 3) * 16;

    f32x4 acc = wave_gemm(sim_bf + (size_t)m0*NN,
                          sxT + ((size_t)b*DIN + d0)*NN, lane);

    const int q = lane >> 4, r = lane & 15;
    const int d = d0 + r, mrow = m0 + q*4;
    #pragma unroll
    for (int reg = 0; reg < 4; ++reg)
        y[((size_t)b*NN + mrow + reg)*DIN + d] = acc[reg];
}

// =======================================================================
// K4: out[b,n,o] = sum_ki [sx;y][b,n,ki] * W2[n,ki,o] + E[n]@bp. 1024 blocks.
// =======================================================================
__global__ __launch_bounds__(256) void k_out2(const float* __restrict__ E,
                                              const float* __restrict__ bp,
                                              const unsigned short* __restrict__ W2,
                                              const float* __restrict__ sxin,
                                              const float* __restrict__ yin,
                                              float* __restrict__ out) {
    const int n = blockIdx.x;
    const int tid = threadIdx.x;
    __shared__ __align__(16) uint4 W2l4[1024];
    __shared__ float vl[BB * 128];
    __shared__ float El2[EMB];

    if (tid < EMB) El2[tid] = E[n*EMB + tid];
    {
        const uint4* src = (const uint4*)(W2 + (size_t)n * 8192);
        #pragma unroll
        for (int r = 0; r < 4; ++r) W2l4[tid + r*256] = src[tid + r*256];
    }
    for (int idx = tid; idx < BB*128; idx += 256) {
        int b_ = idx >> 7, ki = idx & 127;
        vl[idx] = (ki < 64) ? sxin[((size_t)b_*NN + n)*DIN + ki]
                            : yin[((size_t)b_*NN + n)*DIN + (ki - 64)];
    }
    __syncthreads();

    const int b_ = tid >> 5, op = (tid & 31) * 2;
    const unsigned* W2u = (const unsigned*)W2l4;
    float a0 = 0.f, a1 = 0.f;
    #pragma unroll 4
    for (int ki = 0; ki < 128; ++ki) {
        float vv = vl[b_*128 + ki];
        unsigned w2 = W2u[ki*32 + (op >> 1)];
        a0 += vv * __uint_as_float(w2 << 16);
        a1 += vv * __uint_as_float(w2 & 0xffff0000u);
    }
    float b0 = 0.f, b1 = 0.f;
    #pragma unroll
    for (int d = 0; d < EMB; ++d) {
        float e = El2[d];
        b0 += e * bp[d*DOUT + op];
        b1 += e * bp[d*DOUT + op + 1];
    }
    *(float2*)&out[((size_t)b_*NN + n)*DOUT + op] = make_float2(a0 + b0, a1 + b1);
}

extern "C" void kernel_launch(void* const* d_in, const int* in_sizes, int n_in,
                              void* d_out, int out_size, void* d_ws, size_t ws_size,
                              hipStream_t stream) {
    (void)in_sizes; (void)n_in; (void)out_size; (void)ws_size;
    const float* x  = (const float*)d_in[0];
    const float* E  = (const float*)d_in[1];
    const float* pa = (const float*)d_in[2];
    const float* wp = (const float*)d_in[3];
    const float* bp = (const float*)d_in[4];
    float* out = (float*)d_out;

    unsigned short* ws16   = (unsigned short*)d_ws;
    unsigned short* sim_bf = ws16;                       // 1,048,576 us
    unsigned short* xzT    = sim_bf + (size_t)NN*NN;     //   524,288 us
    unsigned short* sxT    = xzT + (size_t)BB*DIN*NN;    //   524,288 us
    unsigned short* Sub    = sxT + (size_t)BB*DIN*NN;    // 8,388,608 us
    unsigned short* W2     = Sub + (size_t)BB*NN*NN;     // 8,388,608 us
    float* sx = (float*)(W2 + (size_t)NN*2*DIN*DOUT);    //   524,288 f
    float* y  = sx + (size_t)BB*NN*DIN;                  //   524,288 f

    k_front<<<1792, 256, 0, stream>>>(E, pa, x, wp, sim_bf, Sub, xzT, W2);
    k_sx5<<<512, 256, 0, stream>>>(Sub, xzT, sx, sxT);
    k_y5<<<512, 256, 0, stream>>>(sim_bf, sxT, y);
    k_out2<<<NN, 256, 0, stream>>>(E, bp, W2, sx, y, out);
}